// Round 14
// baseline (391.054 us; speedup 1.0000x reference)
//
#include <hip/hip_runtime.h>
#include <hip/hip_bf16.h>
#include <math.h>

#define B_ 16
#define S_ 2048
#define D_ 512
#define E_ 8
#define H_ 2048

typedef __bf16 bf16_t;
typedef __bf16 bf16x8 __attribute__((ext_vector_type(8)));
typedef __bf16 bf16x4v __attribute__((ext_vector_type(4)));
typedef float f32x4 __attribute__((ext_vector_type(4)));

__device__ __forceinline__ void gload_lds16(const void* g, void* l) {
  __builtin_amdgcn_global_load_lds((const __attribute__((address_space(1))) void*)g,
                                   (__attribute__((address_space(3))) void*)l,
                                   16, 0, 0);
}

#define BAR() __builtin_amdgcn_s_barrier()
#define LGKM0() do { asm volatile("s_waitcnt lgkmcnt(0)" ::: "memory"); \
                     __builtin_amdgcn_sched_barrier(0); } while (0)
#define LGKMW() asm volatile("s_waitcnt lgkmcnt(0)" ::: "memory")
#define LGKM8() asm volatile("s_waitcnt lgkmcnt(8)" ::: "memory")
#define VM4() asm volatile("s_waitcnt vmcnt(4)" ::: "memory")
#define VM0() asm volatile("s_waitcnt vmcnt(0)" ::: "memory")
#define PRIO1() __builtin_amdgcn_s_setprio(1)
#define PRIO0() __builtin_amdgcn_s_setprio(0)

// fast GELU (tanh-form, max dev from exact-erf GELU ~5e-4)
__device__ __forceinline__ float fast_gelu(float v) {
  const float t = 1.5957691216f * v * (1.0f + 0.044715f * v * v);
  return v * __builtin_amdgcn_rcpf(1.0f + __expf(-t));
}

// ---------------- merged prep: x cvt+pool partials, w1/w2 transpose+cvt ----------------
__global__ void prep_kernel(const float* __restrict__ x, bf16_t* __restrict__ xbf,
                            float* __restrict__ pool,
                            const float* __restrict__ w1, bf16_t* __restrict__ w1t,
                            const float* __restrict__ w2, bf16_t* __restrict__ w2t) {
  const int id = blockIdx.x;
  const int tid = threadIdx.x;
  if (id < 256) {
    const int ch = id & 15, b = id >> 4;
    const int cg = tid & 127;
    const int rg = tid >> 7;
    const size_t base = ((size_t)b * S_ + (size_t)ch * 128 + rg * 32) * D_ + cg * 4;
    const float* xp = x + base;
    bf16_t* op = xbf + base;
    float s0 = 0.f, s1 = 0.f, s2 = 0.f, s3 = 0.f;
#pragma unroll 4
    for (int r = 0; r < 32; ++r) {
      float4 v = *reinterpret_cast<const float4*>(xp + (size_t)r * D_);
      s0 += v.x; s1 += v.y; s2 += v.z; s3 += v.w;
      bf16x4v o;
      o[0] = (bf16_t)v.x; o[1] = (bf16_t)v.y; o[2] = (bf16_t)v.z; o[3] = (bf16_t)v.w;
      *reinterpret_cast<bf16x4v*>(op + (size_t)r * D_) = o;
    }
    float* pp = pool + ((size_t)b * 64 + ch * 4 + rg) * D_ + cg * 4;
    pp[0] = s0; pp[1] = s1; pp[2] = s2; pp[3] = s3;
    return;
  }
  int t = id - 256;
  const float* in; bf16_t* outp; int R, C, r0, c0;
  if (t < 1024) {
    const int e = t >> 7, u = t & 127;
    R = D_; C = H_;
    r0 = (u >> 4) * 64; c0 = (u & 15) * 128;
    in = w1 + (size_t)e * R * C; outp = w1t + (size_t)e * R * C;
  } else {
    t -= 1024;
    const int e = t >> 7, u = t & 127;
    R = H_; C = D_;
    r0 = (u >> 2) * 64; c0 = (u & 3) * 128;
    in = w2 + (size_t)e * R * C; outp = w2t + (size_t)e * R * C;
  }
  const int cb2 = tid >> 4;   // 0..31
  const int rb  = tid & 15;   // 0..15
  const float* ip = in + (size_t)(r0 + rb * 4) * C + c0 + cb2 * 4;
  f32x4 v0 = *reinterpret_cast<const f32x4*>(ip);
  f32x4 v1 = *reinterpret_cast<const f32x4*>(ip + C);
  f32x4 v2 = *reinterpret_cast<const f32x4*>(ip + 2 * C);
  f32x4 v3 = *reinterpret_cast<const f32x4*>(ip + 3 * C);
  bf16_t* opb = outp + (size_t)(c0 + cb2 * 4) * R + r0 + rb * 4;
#pragma unroll
  for (int i = 0; i < 4; ++i) {
    bf16x4v o;
    o[0] = (bf16_t)v0[i]; o[1] = (bf16_t)v1[i]; o[2] = (bf16_t)v2[i]; o[3] = (bf16_t)v3[i];
    *reinterpret_cast<bf16x4v*>(opb + (size_t)i * R) = o;
  }
}

// ---------------- gating: logits + top-2 + softmax (shuffle reduce) ----------------
__global__ void gate_kernel(const float* __restrict__ pool, const float* __restrict__ gw,
                            const float* __restrict__ gb, int* __restrict__ route_e,
                            float* __restrict__ route_w) {
  const int b = blockIdx.x;
  const int d = threadIdx.x;
  const int lane = d & 63, wave = d >> 6;
  float p = 0.f;
#pragma unroll
  for (int c = 0; c < 64; ++c) p += pool[((size_t)b * 64 + c) * D_ + d];
  p *= (1.0f / (float)S_);

  __shared__ float wsum[8][8];
  __shared__ float logits[E_];
#pragma unroll
  for (int e = 0; e < E_; ++e) {
    float v = p * gw[d * E_ + e];
#pragma unroll
    for (int off = 32; off >= 1; off >>= 1) v += __shfl_xor(v, off);
    if (lane == 0) wsum[wave][e] = v;
  }
  __syncthreads();
  if (d < E_) {
    float l = gb[d];
#pragma unroll
    for (int w = 0; w < 8; ++w) l += wsum[w][d];
    logits[d] = l;
  }
  __syncthreads();
  if (d == 0) {
    int i0 = 0; float v0 = logits[0];
    for (int e = 1; e < E_; ++e) if (logits[e] > v0) { v0 = logits[e]; i0 = e; }
    int i1 = -1; float v1 = -3.0e38f;
    for (int e = 0; e < E_; ++e) if (e != i0 && logits[e] > v1) { v1 = logits[e]; i1 = e; }
    const float z = expf(v1 - v0);
    const float inv = 1.0f / (1.0f + z);
    route_e[2 * b] = i0; route_e[2 * b + 1] = i1;
    route_w[2 * b] = inv; route_w[2 * b + 1] = z * inv;
  }
}

// ================= shared GEMM machinery =================
#define GEMM_THREAD_CONSTS() \
  const int tid = threadIdx.x; \
  const int lane = tid & 63; \
  const int wave = tid >> 6; \
  const int wr = wave >> 2; \
  const int wc = wave & 3; \
  const int fl = lane & 15; \
  const int hi = (lane >> 4) & 3; \
  const int flb = fl * 128; \
  const int xorv = (fl & 7) << 4; \
  const int koff0 = (hi * 16) ^ xorv; \
  const int koff1 = (64 + hi * 16) ^ xorv; \
  const int r0s = tid >> 3; \
  const int g0s = ((tid & 7) ^ (r0s & 7)) << 3; \
  const int r1s = 64 + (tid >> 3); \
  const int g1s = ((tid & 7) ^ (r1s & 7)) << 3;

#define STAGE_HALF(g, ld, row0, col0, lo) do { \
  gload_lds16((g) + (size_t)((row0) + r0s) * (ld) + (col0) + g0s, smem + (lo) + tid * 16); \
  gload_lds16((g) + (size_t)((row0) + r1s) * (ld) + (col0) + g1s, smem + (lo) + 8192 + tid * 16); \
} while (0)

#define RD_A(mh) do { \
  const char* _pA = smem + ((((t) & 1) * 2 + wr) << 14); \
  _Pragma("unroll") for (int mq = 0; mq < 4; ++mq) { \
    a[mq][0] = *reinterpret_cast<const bf16x8*>(_pA + (mh) * 8192 + mq * 2048 + flb + koff0); \
    a[mq][1] = *reinterpret_cast<const bf16x8*>(_pA + (mh) * 8192 + mq * 2048 + flb + koff1); \
  } } while (0)

#define RD_B(nh) do { \
  const char* _pB = smem + 65536 + ((((t) & 1) * 2 + (wc >> 1)) << 14) + ((wc & 1) << 13); \
  _Pragma("unroll") for (int nq = 0; nq < 2; ++nq) { \
    bb[nh][nq][0] = *reinterpret_cast<const bf16x8*>(_pB + (nh) * 4096 + nq * 2048 + flb + koff0); \
    bb[nh][nq][1] = *reinterpret_cast<const bf16x8*>(_pB + (nh) * 4096 + nq * 2048 + flb + koff1); \
  } } while (0)

#define MFMA_Q(mh, nh) do { \
  _Pragma("unroll") for (int mq = 0; mq < 4; ++mq) \
  _Pragma("unroll") for (int nq = 0; nq < 2; ++nq) { \
    acc[(mh)*4+mq][(nh)*2+nq] = __builtin_amdgcn_mfma_f32_16x16x32_bf16( \
        a[mq][0], bb[nh][nq][0], acc[(mh)*4+mq][(nh)*2+nq], 0, 0, 0); \
    acc[(mh)*4+mq][(nh)*2+nq] = __builtin_amdgcn_mfma_f32_16x16x32_bf16( \
        a[mq][1], bb[nh][nq][1], acc[(mh)*4+mq][(nh)*2+nq], 0, 0, 0); \
  } } while (0)

// ---------------- GEMM1: 256x256 tiles + fast GELU -> h(bf16), LDS-repacked stores ----
// NTM m-tiles x NTN n-tiles per group. A rows offset by mbase; C rows local to launch.
template<int NTM, int NTN>
__global__ __launch_bounds__(512, 2) void gemm1_kernel(
    const bf16_t* __restrict__ xbf, const bf16_t* __restrict__ w1t,
    const float* __restrict__ b1, const int* __restrict__ route_e,
    bf16_t* __restrict__ h_ws, int g0, int mbase, size_t cstride) {
  __shared__ alignas(16) char smem[131072];
  const int TILES = NTM * NTN;
  const int nwg = gridDim.x;
  const int id = blockIdx.x;
  const int swz = (id & 7) * (nwg >> 3) + (id >> 3);
  const int lg = swz / TILES;
  const int tile = swz % TILES;
  const int m0 = (tile / NTN) * 256;
  const int n0 = (tile % NTN) * 256;
  const int g = g0 + lg;
  const int b = g >> 1;
  const int e = route_e[g];
  const bf16_t* Ax = xbf + (size_t)b * S_ * D_;
  const bf16_t* Bw = w1t + (size_t)e * H_ * D_;
  bf16_t* C = h_ws + (size_t)lg * cstride;

  GEMM_THREAD_CONSTS();

  f32x4 acc[8][4];
#pragma unroll
  for (int i = 0; i < 8; ++i)
#pragma unroll
    for (int j = 0; j < 4; ++j) acc[i][j] = f32x4{0.f, 0.f, 0.f, 0.f};
  bf16x8 a[4][2], bb[2][2][2];

#define ST_A1(tt, hh) STAGE_HALF(Ax, D_, mbase + m0 + (hh) * 128, (tt) * 64, ((((tt) & 1) * 2 + (hh)) << 14))
#define ST_B1(tt, hh) STAGE_HALF(Bw, D_, n0 + (hh) * 128, (tt) * 64, 65536 + ((((tt) & 1) * 2 + (hh)) << 14))

  const int NT = D_ / 64;  // 8
  ST_A1(0, 0); ST_A1(0, 1); ST_B1(0, 0); ST_B1(0, 1);
  ST_B1(1, 0); ST_B1(1, 1);
  VM4(); BAR();

  for (int t = 0; t < NT; ++t) {
    RD_A(0); RD_B(0);
    if (t + 1 < NT) ST_A1(t + 1, 0);
    BAR(); LGKM0(); PRIO1(); MFMA_Q(0, 0); PRIO0(); BAR();
    RD_B(1);
    if (t + 1 < NT) ST_A1(t + 1, 1);
    BAR(); LGKM0(); PRIO1(); MFMA_Q(0, 1); PRIO0(); BAR();
    RD_A(1);
    if (t + 2 < NT) ST_B1(t + 2, 0);
    BAR(); LGKM0(); PRIO1(); MFMA_Q(1, 0); PRIO0(); BAR();
    if (t + 2 < NT) ST_B1(t + 2, 1);
    if (t < NT - 2) { VM4(); } else if (t == NT - 2) { VM0(); }
    BAR(); PRIO1(); MFMA_Q(1, 1); PRIO0(); BAR();
  }
#undef ST_A1
#undef ST_B1

  // epilogue: bias + fast GELU -> LDS [256][512B] (XOR bits 6:5 by (row>>2)&3) -> 16B stores
  const int rb2 = hi * 4;
#pragma unroll
  for (int ni = 0; ni < 4; ++ni) {
    const int col = wc * 64 + ni * 16 + fl;
    const float bias = b1[e * H_ + n0 + col];
    const int cb = col * 2;
#pragma unroll
    for (int mi = 0; mi < 8; ++mi) {
#pragma unroll
      for (int j = 0; j < 4; ++j) {
        const int row = wr * 128 + mi * 16 + rb2 + j;
        const float v = acc[mi][ni][j] + bias;
        const int ad = (row << 9) + (cb ^ (((row >> 2) & 3) << 5));
        *reinterpret_cast<bf16_t*>(smem + ad) = (bf16_t)fast_gelu(v);
      }
    }
  }
  LGKMW(); BAR();
#pragma unroll
  for (int i = 0; i < 16; ++i) {
    const int byte = i * 8192 + tid * 16;
    const int row = byte >> 9;
    const int colb = byte & 511;
    const int ad = (row << 9) + (colb ^ (((row >> 2) & 3) << 5));
    const bf16x8 vv = *reinterpret_cast<const bf16x8*>(smem + ad);
    *reinterpret_cast<bf16x8*>((char*)C + ((size_t)(m0 + row) * H_ + n0) * 2 + colb) = vv;
  }
}

// ---------------- GEMM2s: BM=128, BN=256, full-K (2 experts), no RMW ----------------
template<int KNT>
__global__ __launch_bounds__(512, 2) void gemm2s_kernel(
    const bf16_t* __restrict__ h_ws, const bf16_t* __restrict__ w2t,
    const float* __restrict__ b2, const int* __restrict__ route_e,
    const float* __restrict__ route_w, float* __restrict__ out, int srow) {
  __shared__ alignas(16) char smem[98304];
  const int nwg = gridDim.x;
  const int id = blockIdx.x;
  const int swz = (id & 7) * (nwg >> 3) + (id >> 3);
  const int lb = swz >> 4;
  const int tile = swz & 15;
  const int m0 = (tile >> 1) * 128;
  const int n0 = (tile & 1) * 256;
  const int e0 = route_e[2 * lb], e1 = route_e[2 * lb + 1];
  const float wg0 = route_w[2 * lb], wg1 = route_w[2 * lb + 1];
  const float ratio = wg1 / wg0;
  const bf16_t* Ae1 = h_ws + (size_t)(lb * 2 + 1) * 1024 * H_;
  const bf16_t* Ae0 = h_ws + (size_t)(lb * 2 + 0) * 1024 * H_;
  const bf16_t* Be1 = w2t + (size_t)e1 * D_ * H_;
  const bf16_t* Be0 = w2t + (size_t)e0 * D_ * H_;

  GEMM_THREAD_CONSTS();
  (void)koff1;

  f32x4 acc[4][4];
#pragma unroll
  for (int i = 0; i < 4; ++i)
#pragma unroll
    for (int j = 0; j < 4; ++j) acc[i][j] = f32x4{0.f, 0.f, 0.f, 0.f};
  bf16x8 a[4][2], bb[2][2][2];

  const int KH = KNT / 2;  // 32

#define ST_A2S(tt) do { const bf16_t* _ab = ((tt) < KH) ? Ae1 : Ae0; \
  STAGE_HALF(_ab, H_, m0, ((tt) & (KH - 1)) * 64, (((tt) & 1) << 14)); } while (0)
#define ST_B2S(tt, hh) do { const bf16_t* _bbp = ((tt) < KH) ? Be1 : Be0; \
  STAGE_HALF(_bbp, H_, n0 + (hh) * 128, ((tt) & (KH - 1)) * 64, 32768 + ((((tt) & 1) * 2 + (hh)) << 14)); } while (0)

#define RD_AS() do { \
  const char* _pA = smem + (((t) & 1) << 14); \
  _Pragma("unroll") for (int mq = 0; mq < 4; ++mq) { \
    a[mq][0] = *reinterpret_cast<const bf16x8*>(_pA + wr * 8192 + mq * 2048 + flb + koff0); \
    a[mq][1] = *reinterpret_cast<const bf16x8*>(_pA + wr * 8192 + mq * 2048 + flb + koff1); \
  } } while (0)

#define RD_BS(nh) do { \
  const char* _pB = smem + 32768 + ((((t) & 1) * 2 + (wc >> 1)) << 14) + ((wc & 1) << 13); \
  _Pragma("unroll") for (int nq = 0; nq < 2; ++nq) { \
    bb[nh][nq][0] = *reinterpret_cast<const bf16x8*>(_pB + (nh) * 4096 + nq * 2048 + flb + koff0); \
    bb[nh][nq][1] = *reinterpret_cast<const bf16x8*>(_pB + (nh) * 4096 + nq * 2048 + flb + koff1); \
  } } while (0)

#define MFMA_S(nh) do { \
  _Pragma("unroll") for (int mq = 0; mq < 4; ++mq) \
  _Pragma("unroll") for (int nq = 0; nq < 2; ++nq) { \
    acc[mq][(nh)*2+nq] = __builtin_amdgcn_mfma_f32_16x16x32_bf16( \
        a[mq][0], bb[nh][nq][0], acc[mq][(nh)*2+nq], 0, 0, 0); \
    acc[mq][(nh)*2+nq] = __builtin_amdgcn_mfma_f32_16x16x32_bf16( \
        a[mq][1], bb[nh][nq][1], acc[mq][(nh)*2+nq], 0, 0, 0); \
  } } while (0)

  const int NT = KNT;
  ST_A2S(0); ST_B2S(0, 0); ST_B2S(0, 1);
  ST_B2S(1, 0); ST_B2S(1, 1);
  VM4(); BAR();

  for (int t = 0; t < NT; ++t) {
    RD_AS(); RD_BS(0);
    if (t + 1 < NT) ST_A2S(t + 1);
    LGKM8(); BAR(); LGKM0(); PRIO1(); MFMA_S(0); PRIO0(); BAR();
    RD_BS(1);
    if (t + 2 < NT) { ST_B2S(t + 2, 0); ST_B2S(t + 2, 1); }
    if (t < NT - 2) { VM4(); } else if (t == NT - 2) { VM0(); }
    BAR(); LGKM0(); PRIO1(); MFMA_S(1); PRIO0();
    if (t == KH - 1) {
#pragma unroll
      for (int i = 0; i < 4; ++i)
#pragma unroll
        for (int j = 0; j < 4; ++j) acc[i][j] = acc[i][j] * ratio;
    }
    BAR();
  }
#undef ST_A2S
#undef ST_B2S
#undef RD_AS
#undef RD_BS
#undef MFMA_S

  const int rb2 = hi * 4;
  float* Co = out + (size_t)lb * S_ * D_;
#pragma unroll
  for (int ni = 0; ni < 4; ++ni) {
    const int gc = n0 + wc * 64 + ni * 16 + fl;
    const float wb = wg0 * b2[e0 * D_ + gc] + wg1 * b2[e1 * D_ + gc];
#pragma unroll
    for (int mq = 0; mq < 4; ++mq) {
#pragma unroll
      for (int j = 0; j < 4; ++j) {
        const int gr = srow + m0 + wr * 64 + mq * 16 + rb2 + j;
        Co[(size_t)gr * D_ + gc] = wg0 * acc[mq][ni][j] + wb;
      }
    }
  }
}

// ---------------- legacy GEMM2 (per-sample fallback path) ----------------
template<int KNT>
__global__ __launch_bounds__(512, 2) void gemm2_kernel(
    const bf16_t* __restrict__ h_ws, const bf16_t* __restrict__ w2t,
    const float* __restrict__ b2, const int* __restrict__ route_e,
    const float* __restrict__ route_w, float* __restrict__ out, int b0) {
  __shared__ alignas(16) char smem[131072];
  const int nwg = gridDim.x;
  const int id = blockIdx.x;
  const int swz = (id & 7) * (nwg >> 3) + (id >> 3);
  const int lb = swz >> 4;
  const int tile = swz & 15;
  const int m0 = (tile >> 1) * 256;
  const int n0 = (tile & 1) * 256;
  const int smp = b0 + lb;
  const int e0 = route_e[2 * smp], e1 = route_e[2 * smp + 1];
  const float wg0 = route_w[2 * smp], wg1 = route_w[2 * smp + 1];
  const float ratio = wg1 / wg0;
  const bf16_t* Ae1 = h_ws + (size_t)(lb * 2 + 1) * S_ * H_;
  const bf16_t* Ae0 = h_ws + (size_t)(lb * 2 + 0) * S_ * H_;
  const bf16_t* Be1 = w2t + (size_t)e1 * D_ * H_;
  const bf16_t* Be0 = w2t + (size_t)e0 * D_ * H_;

  GEMM_THREAD_CONSTS();

  f32x4 acc[8][4];
#pragma unroll
  for (int i = 0; i < 8; ++i)
#pragma unroll
    for (int j = 0; j < 4; ++j) acc[i][j] = f32x4{0.f, 0.f, 0.f, 0.f};
  bf16x8 a[4][2], bb[2][2][2];

  const int KH = KNT / 2;

#define ST_A2(tt, hh) do { const bf16_t* _ab = ((tt) < KH) ? Ae1 : Ae0; \
  STAGE_HALF(_ab, H_, m0 + (hh) * 128, ((tt) & (KH - 1)) * 64, ((((tt) & 1) * 2 + (hh)) << 14)); } while (0)
#define ST_B2(tt, hh) do { const bf16_t* _bbp = ((tt) < KH) ? Be1 : Be0; \
  STAGE_HALF(_bbp, H_, n0 + (hh) * 128, ((tt) & (KH - 1)) * 64, 65536 + ((((tt) & 1) * 2 + (hh)) << 14)); } while (0)

  const int NT = KNT;
  ST_A2(0, 0); ST_A2(0, 1); ST_B2(0, 0); ST_B2(0, 1);
  ST_B2(1, 0); ST_B2(1, 1);
  VM4(); BAR();

  for (int t = 0; t < NT; ++t) {
    RD_A(0); RD_B(0);
    if (t + 1 < NT) ST_A2(t + 1, 0);
    BAR(); LGKM0(); PRIO1(); MFMA_Q(0, 0); PRIO0(); BAR();
    RD_B(1);
    if (t + 1 < NT) ST_A2(t + 1, 1);
    BAR(); LGKM0(); PRIO1(); MFMA_Q(0, 1); PRIO0(); BAR();
    RD_A(1);
    if (t + 2 < NT) ST_B2(t + 2, 0);
    BAR(); LGKM0(); PRIO1(); MFMA_Q(1, 0); PRIO0(); BAR();
    if (t + 2 < NT) ST_B2(t + 2, 1);
    if (t < NT - 2) { VM4(); } else if (t == NT - 2) { VM0(); }
    BAR(); PRIO1(); MFMA_Q(1, 1); PRIO0();
    if (t == KH - 1) {
#pragma unroll
      for (int i = 0; i < 8; ++i)
#pragma unroll
        for (int j = 0; j < 4; ++j) acc[i][j] = acc[i][j] * ratio;
    }
    BAR();
  }
#undef ST_A2
#undef ST_B2

  const int rb2 = hi * 4;
  float* Co = out + (size_t)smp * S_ * D_;
#pragma unroll
  for (int ni = 0; ni < 4; ++ni) {
    const int gc = n0 + wc * 64 + ni * 16 + fl;
    const float wb = wg0 * b2[e0 * D_ + gc] + wg1 * b2[e1 * D_ + gc];
#pragma unroll
    for (int mi = 0; mi < 8; ++mi) {
#pragma unroll
      for (int j = 0; j < 4; ++j) {
        const int gr = m0 + wr * 128 + mi * 16 + rb2 + j;
        Co[(size_t)gr * D_ + gc] = wg0 * acc[mi][ni][j] + wb;
      }
    }
  }
}

extern "C" void kernel_launch(void* const* d_in, const int* in_sizes, int n_in,
                              void* d_out, int out_size, void* d_ws, size_t ws_size,
                              hipStream_t stream) {
  const float* x      = (const float*)d_in[0];
  const float* gate_w = (const float*)d_in[1];
  const float* gate_b = (const float*)d_in[2];
  const float* w1     = (const float*)d_in[3];
  const float* b1     = (const float*)d_in[4];
  const float* w2     = (const float*)d_in[5];
  const float* b2     = (const float*)d_in[6];
  float* out = (float*)d_out;
  char* ws = (char*)d_ws;

  bf16_t* xbf    = (bf16_t*)(ws);                 // 33,554,432
  bf16_t* w1t    = (bf16_t*)(ws + 33554432);      // 16,777,216
  bf16_t* w2t    = (bf16_t*)(ws + 50331648);      // 16,777,216
  float*  pool   = (float*)(ws + 67108864);       // 2,097,152
  int*    route_e = (int*)(ws + 69206016);
  float*  route_w = (float*)(ws + 69206144);
  const size_t h_off = 69206272;
  bf16_t* h_ws   = (bf16_t*)(ws + h_off);

  prep_kernel<<<2304, 512, 0, stream>>>(x, xbf, pool, w1, w1t, w2, w2t);
  gate_kernel<<<B_, 512, 0, stream>>>(pool, gate_w, gate_b, route_e, route_w);

  const bool split = ws_size >= h_off + (size_t)134217728;  // h row-half = 128 MiB
  if (split) {
    // S-split pipeline: gemm1 full-H for a row-half, gemm2s full-K no-RMW. All full-GPU.
    gemm1_kernel<4, 8><<<1024, 512, 0, stream>>>(xbf, w1t, b1, route_e, h_ws, 0, 0, (size_t)1024 * H_);
    gemm2s_kernel<64><<<256, 512, 0, stream>>>(h_ws, w2t, b2, route_e, route_w, out, 0);
    gemm1_kernel<4, 8><<<1024, 512, 0, stream>>>(xbf, w1t, b1, route_e, h_ws, 0, 1024, (size_t)1024 * H_);
    gemm2s_kernel<64><<<256, 512, 0, stream>>>(h_ws, w2t, b2, route_e, route_w, out, 1024);
  } else {
    const size_t per_b = (size_t)2 * S_ * H_ * sizeof(bf16_t);
    size_t avail = (ws_size > h_off) ? (ws_size - h_off) : 0;
    int nb = (int)(avail / per_b);
    if (nb < 1) nb = 1;
    if (nb > B_) nb = B_;
    for (int b0 = 0; b0 < B_; b0 += nb) {
      const int cb = (B_ - b0 < nb) ? (B_ - b0) : nb;
      gemm1_kernel<8, 8><<<64 * cb * 2, 512, 0, stream>>>(xbf, w1t, b1, route_e, h_ws, b0 * 2, 0, (size_t)S_ * H_);
      gemm2_kernel<64><<<16 * cb, 512, 0, stream>>>(h_ws, w2t, b2, route_e, route_w, out, b0);
    }
  }
}

// Round 16
// 390.822 us; speedup vs baseline: 1.0006x; 1.0006x over previous
//
#include <hip/hip_runtime.h>
#include <hip/hip_bf16.h>
#include <math.h>

#define B_ 16
#define S_ 2048
#define D_ 512
#define E_ 8
#define H_ 2048

typedef __bf16 bf16_t;
typedef __bf16 bf16x8 __attribute__((ext_vector_type(8)));
typedef __bf16 bf16x4v __attribute__((ext_vector_type(4)));
typedef float f32x4 __attribute__((ext_vector_type(4)));

__device__ __forceinline__ void gload_lds16(const void* g, void* l) {
  __builtin_amdgcn_global_load_lds((const __attribute__((address_space(1))) void*)g,
                                   (__attribute__((address_space(3))) void*)l,
                                   16, 0, 0);
}

#define BAR() __builtin_amdgcn_s_barrier()
#define LGKM0() do { asm volatile("s_waitcnt lgkmcnt(0)" ::: "memory"); \
                     __builtin_amdgcn_sched_barrier(0); } while (0)
#define LGKMW() asm volatile("s_waitcnt lgkmcnt(0)" ::: "memory")
#define LGKM8() asm volatile("s_waitcnt lgkmcnt(8)" ::: "memory")
#define VM4() asm volatile("s_waitcnt vmcnt(4)" ::: "memory")
#define VM0() asm volatile("s_waitcnt vmcnt(0)" ::: "memory")
#define PRIO1() __builtin_amdgcn_s_setprio(1)
#define PRIO0() __builtin_amdgcn_s_setprio(0)

// fast GELU (tanh-form, max dev from exact-erf GELU ~5e-4)
__device__ __forceinline__ float fast_gelu(float v) {
  const float t = 1.5957691216f * v * (1.0f + 0.044715f * v * v);
  return v * __builtin_amdgcn_rcpf(1.0f + __expf(-t));
}

// ---------------- merged prep: x cvt+pool partials, w1/w2 transpose+cvt ----------------
__global__ void prep_kernel(const float* __restrict__ x, bf16_t* __restrict__ xbf,
                            float* __restrict__ pool,
                            const float* __restrict__ w1, bf16_t* __restrict__ w1t,
                            const float* __restrict__ w2, bf16_t* __restrict__ w2t) {
  const int id = blockIdx.x;
  const int tid = threadIdx.x;
  if (id < 256) {
    const int ch = id & 15, b = id >> 4;
    const int cg = tid & 127;
    const int rg = tid >> 7;
    const size_t base = ((size_t)b * S_ + (size_t)ch * 128 + rg * 32) * D_ + cg * 4;
    const float* xp = x + base;
    bf16_t* op = xbf + base;
    float s0 = 0.f, s1 = 0.f, s2 = 0.f, s3 = 0.f;
#pragma unroll 4
    for (int r = 0; r < 32; ++r) {
      float4 v = *reinterpret_cast<const float4*>(xp + (size_t)r * D_);
      s0 += v.x; s1 += v.y; s2 += v.z; s3 += v.w;
      bf16x4v o;
      o[0] = (bf16_t)v.x; o[1] = (bf16_t)v.y; o[2] = (bf16_t)v.z; o[3] = (bf16_t)v.w;
      *reinterpret_cast<bf16x4v*>(op + (size_t)r * D_) = o;
    }
    float* pp = pool + ((size_t)b * 64 + ch * 4 + rg) * D_ + cg * 4;
    pp[0] = s0; pp[1] = s1; pp[2] = s2; pp[3] = s3;
    return;
  }
  int t = id - 256;
  const float* in; bf16_t* outp; int R, C, r0, c0;
  if (t < 1024) {
    const int e = t >> 7, u = t & 127;
    R = D_; C = H_;
    r0 = (u >> 4) * 64; c0 = (u & 15) * 128;
    in = w1 + (size_t)e * R * C; outp = w1t + (size_t)e * R * C;
  } else {
    t -= 1024;
    const int e = t >> 7, u = t & 127;
    R = H_; C = D_;
    r0 = (u >> 2) * 64; c0 = (u & 3) * 128;
    in = w2 + (size_t)e * R * C; outp = w2t + (size_t)e * R * C;
  }
  const int cb2 = tid >> 4;   // 0..31
  const int rb  = tid & 15;   // 0..15
  const float* ip = in + (size_t)(r0 + rb * 4) * C + c0 + cb2 * 4;
  f32x4 v0 = *reinterpret_cast<const f32x4*>(ip);
  f32x4 v1 = *reinterpret_cast<const f32x4*>(ip + C);
  f32x4 v2 = *reinterpret_cast<const f32x4*>(ip + 2 * C);
  f32x4 v3 = *reinterpret_cast<const f32x4*>(ip + 3 * C);
  bf16_t* opb = outp + (size_t)(c0 + cb2 * 4) * R + r0 + rb * 4;
#pragma unroll
  for (int i = 0; i < 4; ++i) {
    bf16x4v o;
    o[0] = (bf16_t)v0[i]; o[1] = (bf16_t)v1[i]; o[2] = (bf16_t)v2[i]; o[3] = (bf16_t)v3[i];
    *reinterpret_cast<bf16x4v*>(opb + (size_t)i * R) = o;
  }
}

// ---------------- gating: logits + top-2 + softmax (shuffle reduce) ----------------
__global__ void gate_kernel(const float* __restrict__ pool, const float* __restrict__ gw,
                            const float* __restrict__ gb, int* __restrict__ route_e,
                            float* __restrict__ route_w) {
  const int b = blockIdx.x;
  const int d = threadIdx.x;
  const int lane = d & 63, wave = d >> 6;
  float p = 0.f;
#pragma unroll
  for (int c = 0; c < 64; ++c) p += pool[((size_t)b * 64 + c) * D_ + d];
  p *= (1.0f / (float)S_);

  __shared__ float wsum[8][8];
  __shared__ float logits[E_];
#pragma unroll
  for (int e = 0; e < E_; ++e) {
    float v = p * gw[d * E_ + e];
#pragma unroll
    for (int off = 32; off >= 1; off >>= 1) v += __shfl_xor(v, off);
    if (lane == 0) wsum[wave][e] = v;
  }
  __syncthreads();
  if (d < E_) {
    float l = gb[d];
#pragma unroll
    for (int w = 0; w < 8; ++w) l += wsum[w][d];
    logits[d] = l;
  }
  __syncthreads();
  if (d == 0) {
    int i0 = 0; float v0 = logits[0];
    for (int e = 1; e < E_; ++e) if (logits[e] > v0) { v0 = logits[e]; i0 = e; }
    int i1 = -1; float v1 = -3.0e38f;
    for (int e = 0; e < E_; ++e) if (e != i0 && logits[e] > v1) { v1 = logits[e]; i1 = e; }
    const float z = expf(v1 - v0);
    const float inv = 1.0f / (1.0f + z);
    route_e[2 * b] = i0; route_e[2 * b + 1] = i1;
    route_w[2 * b] = inv; route_w[2 * b + 1] = z * inv;
  }
}

// ================= shared GEMM machinery =================
#define GEMM_THREAD_CONSTS() \
  const int tid = threadIdx.x; \
  const int lane = tid & 63; \
  const int wave = tid >> 6; \
  const int wr = wave >> 2; \
  const int wc = wave & 3; \
  const int fl = lane & 15; \
  const int hi = (lane >> 4) & 3; \
  const int flb = fl * 128; \
  const int xorv = (fl & 7) << 4; \
  const int koff0 = (hi * 16) ^ xorv; \
  const int koff1 = (64 + hi * 16) ^ xorv; \
  const int r0s = tid >> 3; \
  const int g0s = ((tid & 7) ^ (r0s & 7)) << 3; \
  const int r1s = 64 + (tid >> 3); \
  const int g1s = ((tid & 7) ^ (r1s & 7)) << 3;

#define STAGE_HALF(g, ld, row0, col0, lo) do { \
  gload_lds16((g) + (size_t)((row0) + r0s) * (ld) + (col0) + g0s, smem + (lo) + tid * 16); \
  gload_lds16((g) + (size_t)((row0) + r1s) * (ld) + (col0) + g1s, smem + (lo) + 8192 + tid * 16); \
} while (0)

#define RD_A(mh) do { \
  const char* _pA = smem + ((((t) & 1) * 2 + wr) << 14); \
  _Pragma("unroll") for (int mq = 0; mq < 4; ++mq) { \
    a[mq][0] = *reinterpret_cast<const bf16x8*>(_pA + (mh) * 8192 + mq * 2048 + flb + koff0); \
    a[mq][1] = *reinterpret_cast<const bf16x8*>(_pA + (mh) * 8192 + mq * 2048 + flb + koff1); \
  } } while (0)

#define RD_B(nh) do { \
  const char* _pB = smem + 65536 + ((((t) & 1) * 2 + (wc >> 1)) << 14) + ((wc & 1) << 13); \
  _Pragma("unroll") for (int nq = 0; nq < 2; ++nq) { \
    bb[nh][nq][0] = *reinterpret_cast<const bf16x8*>(_pB + (nh) * 4096 + nq * 2048 + flb + koff0); \
    bb[nh][nq][1] = *reinterpret_cast<const bf16x8*>(_pB + (nh) * 4096 + nq * 2048 + flb + koff1); \
  } } while (0)

#define MFMA_Q(mh, nh) do { \
  _Pragma("unroll") for (int mq = 0; mq < 4; ++mq) \
  _Pragma("unroll") for (int nq = 0; nq < 2; ++nq) { \
    acc[(mh)*4+mq][(nh)*2+nq] = __builtin_amdgcn_mfma_f32_16x16x32_bf16( \
        a[mq][0], bb[nh][nq][0], acc[(mh)*4+mq][(nh)*2+nq], 0, 0, 0); \
    acc[(mh)*4+mq][(nh)*2+nq] = __builtin_amdgcn_mfma_f32_16x16x32_bf16( \
        a[mq][1], bb[nh][nq][1], acc[(mh)*4+mq][(nh)*2+nq], 0, 0, 0); \
  } } while (0)

// ---------------- GEMM1: 256x256 tiles + fast GELU -> h(bf16), LDS-repacked stores ----
// NTM m-tiles x NTN n-tiles per group. A rows offset by mbase; C rows local to launch.
template<int NTM, int NTN>
__global__ __launch_bounds__(512, 2) void gemm1_kernel(
    const bf16_t* __restrict__ xbf, const bf16_t* __restrict__ w1t,
    const float* __restrict__ b1, const int* __restrict__ route_e,
    bf16_t* __restrict__ h_ws, int g0, int mbase, size_t cstride) {
  __shared__ alignas(16) char smem[131072];
  const int TILES = NTM * NTN;
  const int nwg = gridDim.x;
  const int id = blockIdx.x;
  const int swz = (id & 7) * (nwg >> 3) + (id >> 3);
  const int lg = swz / TILES;
  const int tile = swz % TILES;
  const int m0 = (tile / NTN) * 256;
  const int n0 = (tile % NTN) * 256;
  const int g = g0 + lg;
  const int b = g >> 1;
  const int e = route_e[g];
  const bf16_t* Ax = xbf + (size_t)b * S_ * D_;
  const bf16_t* Bw = w1t + (size_t)e * H_ * D_;
  bf16_t* C = h_ws + (size_t)lg * cstride;

  GEMM_THREAD_CONSTS();

  f32x4 acc[8][4];
#pragma unroll
  for (int i = 0; i < 8; ++i)
#pragma unroll
    for (int j = 0; j < 4; ++j) acc[i][j] = f32x4{0.f, 0.f, 0.f, 0.f};
  bf16x8 a[4][2], bb[2][2][2];

#define ST_A1(tt, hh) STAGE_HALF(Ax, D_, mbase + m0 + (hh) * 128, (tt) * 64, ((((tt) & 1) * 2 + (hh)) << 14))
#define ST_B1(tt, hh) STAGE_HALF(Bw, D_, n0 + (hh) * 128, (tt) * 64, 65536 + ((((tt) & 1) * 2 + (hh)) << 14))

  const int NT = D_ / 64;  // 8
  ST_A1(0, 0); ST_A1(0, 1); ST_B1(0, 0); ST_B1(0, 1);
  ST_B1(1, 0); ST_B1(1, 1);
  VM4(); BAR();

  for (int t = 0; t < NT; ++t) {
    RD_A(0); RD_B(0);
    if (t + 1 < NT) ST_A1(t + 1, 0);
    BAR(); LGKM0(); PRIO1(); MFMA_Q(0, 0); PRIO0(); BAR();
    RD_B(1);
    if (t + 1 < NT) ST_A1(t + 1, 1);
    BAR(); LGKM0(); PRIO1(); MFMA_Q(0, 1); PRIO0(); BAR();
    RD_A(1);
    if (t + 2 < NT) ST_B1(t + 2, 0);
    BAR(); LGKM0(); PRIO1(); MFMA_Q(1, 0); PRIO0(); BAR();
    if (t + 2 < NT) ST_B1(t + 2, 1);
    if (t < NT - 2) { VM4(); } else if (t == NT - 2) { VM0(); }
    BAR(); PRIO1(); MFMA_Q(1, 1); PRIO0(); BAR();
  }
#undef ST_A1
#undef ST_B1

  // epilogue: bias + fast GELU -> LDS [256][512B] (XOR bits 6:5 by (row>>2)&3) -> 16B stores
  const int rb2 = hi * 4;
#pragma unroll
  for (int ni = 0; ni < 4; ++ni) {
    const int col = wc * 64 + ni * 16 + fl;
    const float bias = b1[e * H_ + n0 + col];
    const int cb = col * 2;
#pragma unroll
    for (int mi = 0; mi < 8; ++mi) {
#pragma unroll
      for (int j = 0; j < 4; ++j) {
        const int row = wr * 128 + mi * 16 + rb2 + j;
        const float v = acc[mi][ni][j] + bias;
        const int ad = (row << 9) + (cb ^ (((row >> 2) & 3) << 5));
        *reinterpret_cast<bf16_t*>(smem + ad) = (bf16_t)fast_gelu(v);
      }
    }
  }
  LGKMW(); BAR();
#pragma unroll
  for (int i = 0; i < 16; ++i) {
    const int byte = i * 8192 + tid * 16;
    const int row = byte >> 9;
    const int colb = byte & 511;
    const int ad = (row << 9) + (colb ^ (((row >> 2) & 3) << 5));
    const bf16x8 vv = *reinterpret_cast<const bf16x8*>(smem + ad);
    *reinterpret_cast<bf16x8*>((char*)C + ((size_t)(m0 + row) * H_ + n0) * 2 + colb) = vv;
  }
}

// ---------------- GEMM2s: BM=128, BN=256, full-K (2 experts), no RMW ----------------
template<int KNT>
__global__ __launch_bounds__(512, 2) void gemm2s_kernel(
    const bf16_t* __restrict__ h_ws, const bf16_t* __restrict__ w2t,
    const float* __restrict__ b2, const int* __restrict__ route_e,
    const float* __restrict__ route_w, float* __restrict__ out, int srow) {
  __shared__ alignas(16) char smem[98304];
  const int nwg = gridDim.x;
  const int id = blockIdx.x;
  const int swz = (id & 7) * (nwg >> 3) + (id >> 3);
  const int lb = swz >> 4;
  const int tile = swz & 15;
  const int m0 = (tile >> 1) * 128;
  const int n0 = (tile & 1) * 256;
  const int e0 = route_e[2 * lb], e1 = route_e[2 * lb + 1];
  const float wg0 = route_w[2 * lb], wg1 = route_w[2 * lb + 1];
  const float ratio = wg1 / wg0;
  const bf16_t* Ae1 = h_ws + (size_t)(lb * 2 + 1) * 1024 * H_;
  const bf16_t* Ae0 = h_ws + (size_t)(lb * 2 + 0) * 1024 * H_;
  const bf16_t* Be1 = w2t + (size_t)e1 * D_ * H_;
  const bf16_t* Be0 = w2t + (size_t)e0 * D_ * H_;

  GEMM_THREAD_CONSTS();
  (void)koff1;

  f32x4 acc[4][4];
#pragma unroll
  for (int i = 0; i < 4; ++i)
#pragma unroll
    for (int j = 0; j < 4; ++j) acc[i][j] = f32x4{0.f, 0.f, 0.f, 0.f};
  bf16x8 a[4][2], bb[2][2][2];

  const int KH = KNT / 2;  // 32

#define ST_A2S(tt) do { const bf16_t* _ab = ((tt) < KH) ? Ae1 : Ae0; \
  STAGE_HALF(_ab, H_, m0, ((tt) & (KH - 1)) * 64, (((tt) & 1) << 14)); } while (0)
#define ST_B2S(tt, hh) do { const bf16_t* _bbp = ((tt) < KH) ? Be1 : Be0; \
  STAGE_HALF(_bbp, H_, n0 + (hh) * 128, ((tt) & (KH - 1)) * 64, 32768 + ((((tt) & 1) * 2 + (hh)) << 14)); } while (0)

#define RD_AS() do { \
  const char* _pA = smem + (((t) & 1) << 14); \
  _Pragma("unroll") for (int mq = 0; mq < 4; ++mq) { \
    a[mq][0] = *reinterpret_cast<const bf16x8*>(_pA + wr * 8192 + mq * 2048 + flb + koff0); \
    a[mq][1] = *reinterpret_cast<const bf16x8*>(_pA + wr * 8192 + mq * 2048 + flb + koff1); \
  } } while (0)

#define RD_BS(nh) do { \
  const char* _pB = smem + 32768 + ((((t) & 1) * 2 + (wc >> 1)) << 14) + ((wc & 1) << 13); \
  _Pragma("unroll") for (int nq = 0; nq < 2; ++nq) { \
    bb[nh][nq][0] = *reinterpret_cast<const bf16x8*>(_pB + (nh) * 4096 + nq * 2048 + flb + koff0); \
    bb[nh][nq][1] = *reinterpret_cast<const bf16x8*>(_pB + (nh) * 4096 + nq * 2048 + flb + koff1); \
  } } while (0)

#define MFMA_S(nh) do { \
  _Pragma("unroll") for (int mq = 0; mq < 4; ++mq) \
  _Pragma("unroll") for (int nq = 0; nq < 2; ++nq) { \
    acc[mq][(nh)*2+nq] = __builtin_amdgcn_mfma_f32_16x16x32_bf16( \
        a[mq][0], bb[nh][nq][0], acc[mq][(nh)*2+nq], 0, 0, 0); \
    acc[mq][(nh)*2+nq] = __builtin_amdgcn_mfma_f32_16x16x32_bf16( \
        a[mq][1], bb[nh][nq][1], acc[mq][(nh)*2+nq], 0, 0, 0); \
  } } while (0)

  const int NT = KNT;
  ST_A2S(0); ST_B2S(0, 0); ST_B2S(0, 1);
  ST_B2S(1, 0); ST_B2S(1, 1);
  VM4(); BAR();

  for (int t = 0; t < NT; ++t) {
    RD_AS(); RD_BS(0);
    if (t + 1 < NT) ST_A2S(t + 1);
    LGKM8(); BAR(); LGKM0(); PRIO1(); MFMA_S(0); PRIO0(); BAR();
    RD_BS(1);
    if (t + 2 < NT) { ST_B2S(t + 2, 0); ST_B2S(t + 2, 1); }
    if (t < NT - 2) { VM4(); } else if (t == NT - 2) { VM0(); }
    BAR(); LGKM0(); PRIO1(); MFMA_S(1); PRIO0();
    if (t == KH - 1) {
#pragma unroll
      for (int i = 0; i < 4; ++i)
#pragma unroll
        for (int j = 0; j < 4; ++j) acc[i][j] = acc[i][j] * ratio;
    }
    BAR();
  }
#undef ST_A2S
#undef ST_B2S
#undef RD_AS
#undef RD_BS
#undef MFMA_S

  const int rb2 = hi * 4;
  float* Co = out + (size_t)lb * S_ * D_;
#pragma unroll
  for (int ni = 0; ni < 4; ++ni) {
    const int gc = n0 + wc * 64 + ni * 16 + fl;
    const float wb = wg0 * b2[e0 * D_ + gc] + wg1 * b2[e1 * D_ + gc];
#pragma unroll
    for (int mq = 0; mq < 4; ++mq) {
#pragma unroll
      for (int j = 0; j < 4; ++j) {
        const int gr = srow + m0 + wr * 64 + mq * 16 + rb2 + j;
        Co[(size_t)gr * D_ + gc] = wg0 * acc[mq][ni][j] + wb;
      }
    }
  }
}

// ---------------- legacy GEMM2 (per-sample fallback path) ----------------
template<int KNT>
__global__ __launch_bounds__(512, 2) void gemm2_kernel(
    const bf16_t* __restrict__ h_ws, const bf16_t* __restrict__ w2t,
    const float* __restrict__ b2, const int* __restrict__ route_e,
    const float* __restrict__ route_w, float* __restrict__ out, int b0) {
  __shared__ alignas(16) char smem[131072];
  const int nwg = gridDim.x;
  const int id = blockIdx.x;
  const int swz = (id & 7) * (nwg >> 3) + (id >> 3);
  const int lb = swz >> 4;
  const int tile = swz & 15;
  const int m0 = (tile >> 1) * 256;
  const int n0 = (tile & 1) * 256;
  const int smp = b0 + lb;
  const int e0 = route_e[2 * smp], e1 = route_e[2 * smp + 1];
  const float wg0 = route_w[2 * smp], wg1 = route_w[2 * smp + 1];
  const float ratio = wg1 / wg0;
  const bf16_t* Ae1 = h_ws + (size_t)(lb * 2 + 1) * S_ * H_;
  const bf16_t* Ae0 = h_ws + (size_t)(lb * 2 + 0) * S_ * H_;
  const bf16_t* Be1 = w2t + (size_t)e1 * D_ * H_;
  const bf16_t* Be0 = w2t + (size_t)e0 * D_ * H_;

  GEMM_THREAD_CONSTS();

  f32x4 acc[8][4];
#pragma unroll
  for (int i = 0; i < 8; ++i)
#pragma unroll
    for (int j = 0; j < 4; ++j) acc[i][j] = f32x4{0.f, 0.f, 0.f, 0.f};
  bf16x8 a[4][2], bb[2][2][2];

  const int KH = KNT / 2;

#define ST_A2(tt, hh) do { const bf16_t* _ab = ((tt) < KH) ? Ae1 : Ae0; \
  STAGE_HALF(_ab, H_, m0 + (hh) * 128, ((tt) & (KH - 1)) * 64, ((((tt) & 1) * 2 + (hh)) << 14)); } while (0)
#define ST_B2(tt, hh) do { const bf16_t* _bbp = ((tt) < KH) ? Be1 : Be0; \
  STAGE_HALF(_bbp, H_, n0 + (hh) * 128, ((tt) & (KH - 1)) * 64, 65536 + ((((tt) & 1) * 2 + (hh)) << 14)); } while (0)

  const int NT = KNT;
  ST_A2(0, 0); ST_A2(0, 1); ST_B2(0, 0); ST_B2(0, 1);
  ST_B2(1, 0); ST_B2(1, 1);
  VM4(); BAR();

  for (int t = 0; t < NT; ++t) {
    RD_A(0); RD_B(0);
    if (t + 1 < NT) ST_A2(t + 1, 0);
    BAR(); LGKM0(); PRIO1(); MFMA_Q(0, 0); PRIO0(); BAR();
    RD_B(1);
    if (t + 1 < NT) ST_A2(t + 1, 1);
    BAR(); LGKM0(); PRIO1(); MFMA_Q(0, 1); PRIO0(); BAR();
    RD_A(1);
    if (t + 2 < NT) ST_B2(t + 2, 0);
    BAR(); LGKM0(); PRIO1(); MFMA_Q(1, 0); PRIO0(); BAR();
    if (t + 2 < NT) ST_B2(t + 2, 1);
    if (t < NT - 2) { VM4(); } else if (t == NT - 2) { VM0(); }
    BAR(); PRIO1(); MFMA_Q(1, 1); PRIO0();
    if (t == KH - 1) {
#pragma unroll
      for (int i = 0; i < 8; ++i)
#pragma unroll
        for (int j = 0; j < 4; ++j) acc[i][j] = acc[i][j] * ratio;
    }
    BAR();
  }
#undef ST_A2
#undef ST_B2

  const int rb2 = hi * 4;
  float* Co = out + (size_t)smp * S_ * D_;
#pragma unroll
  for (int ni = 0; ni < 4; ++ni) {
    const int gc = n0 + wc * 64 + ni * 16 + fl;
    const float wb = wg0 * b2[e0 * D_ + gc] + wg1 * b2[e1 * D_ + gc];
#pragma unroll
    for (int mi = 0; mi < 8; ++mi) {
#pragma unroll
      for (int j = 0; j < 4; ++j) {
        const int gr = m0 + wr * 128 + mi * 16 + rb2 + j;
        Co[(size_t)gr * D_ + gc] = wg0 * acc[mi][ni][j] + wb;
      }
    }
  }
}

extern "C" void kernel_launch(void* const* d_in, const int* in_sizes, int n_in,
                              void* d_out, int out_size, void* d_ws, size_t ws_size,
                              hipStream_t stream) {
  const float* x      = (const float*)d_in[0];
  const float* gate_w = (const float*)d_in[1];
  const float* gate_b = (const float*)d_in[2];
  const float* w1     = (const float*)d_in[3];
  const float* b1     = (const float*)d_in[4];
  const float* w2     = (const float*)d_in[5];
  const float* b2     = (const float*)d_in[6];
  float* out = (float*)d_out;
  char* ws = (char*)d_ws;

  bf16_t* xbf    = (bf16_t*)(ws);                 // 33,554,432
  bf16_t* w1t    = (bf16_t*)(ws + 33554432);      // 16,777,216
  bf16_t* w2t    = (bf16_t*)(ws + 50331648);      // 16,777,216
  float*  pool   = (float*)(ws + 67108864);       // 2,097,152
  int*    route_e = (int*)(ws + 69206016);
  float*  route_w = (float*)(ws + 69206144);
  const size_t h_off = 69206272;
  bf16_t* h_ws   = (bf16_t*)(ws + h_off);

  prep_kernel<<<2304, 512, 0, stream>>>(x, xbf, pool, w1, w1t, w2, w2t);
  gate_kernel<<<B_, 512, 0, stream>>>(pool, gate_w, gate_b, route_e, route_w);

  const bool split = ws_size >= h_off + (size_t)134217728;  // h row-half = 128 MiB
  if (split) {
    // S-split pipeline: gemm1 full-H for a row-half, gemm2s full-K no-RMW. All full-GPU.
    gemm1_kernel<4, 8><<<1024, 512, 0, stream>>>(xbf, w1t, b1, route_e, h_ws, 0, 0, (size_t)1024 * H_);
    gemm2s_kernel<64><<<256, 512, 0, stream>>>(h_ws, w2t, b2, route_e, route_w, out, 0);
    gemm1_kernel<4, 8><<<1024, 512, 0, stream>>>(xbf, w1t, b1, route_e, h_ws, 0, 1024, (size_t)1024 * H_);
    gemm2s_kernel<64><<<256, 512, 0, stream>>>(h_ws, w2t, b2, route_e, route_w, out, 1024);
  } else {
    const size_t per_b = (size_t)2 * S_ * H_ * sizeof(bf16_t);
    size_t avail = (ws_size > h_off) ? (ws_size - h_off) : 0;
    int nb = (int)(avail / per_b);
    if (nb < 1) nb = 1;
    if (nb > B_) nb = B_;
    for (int b0 = 0; b0 < B_; b0 += nb) {
      const int cb = (B_ - b0 < nb) ? (B_ - b0) : nb;
      gemm1_kernel<8, 8><<<64 * cb * 2, 512, 0, stream>>>(xbf, w1t, b1, route_e, h_ws, b0 * 2, 0, (size_t)S_ * H_);
      gemm2_kernel<64><<<16 * cb, 512, 0, stream>>>(h_ws, w2t, b2, route_e, route_w, out, b0);
    }
  }
}

// Round 17
// 390.390 us; speedup vs baseline: 1.0017x; 1.0011x over previous
//
#include <hip/hip_runtime.h>
#include <hip/hip_bf16.h>
#include <math.h>

#define B_ 16
#define S_ 2048
#define D_ 512
#define E_ 8
#define H_ 2048

typedef __bf16 bf16_t;
typedef __bf16 bf16x8 __attribute__((ext_vector_type(8)));
typedef __bf16 bf16x4v __attribute__((ext_vector_type(4)));
typedef float f32x4 __attribute__((ext_vector_type(4)));

__device__ __forceinline__ void gload_lds16(const void* g, void* l) {
  __builtin_amdgcn_global_load_lds((const __attribute__((address_space(1))) void*)g,
                                   (__attribute__((address_space(3))) void*)l,
                                   16, 0, 0);
}

#define BAR() __builtin_amdgcn_s_barrier()
#define LGKM0() do { asm volatile("s_waitcnt lgkmcnt(0)" ::: "memory"); \
                     __builtin_amdgcn_sched_barrier(0); } while (0)
#define LGKMW() asm volatile("s_waitcnt lgkmcnt(0)" ::: "memory")
#define LGKM8() asm volatile("s_waitcnt lgkmcnt(8)" ::: "memory")
#define VM4() asm volatile("s_waitcnt vmcnt(4)" ::: "memory")
#define VM0() asm volatile("s_waitcnt vmcnt(0)" ::: "memory")
#define PRIO1() __builtin_amdgcn_s_setprio(1)
#define PRIO0() __builtin_amdgcn_s_setprio(0)

// fast GELU (tanh-form, max dev from exact-erf GELU ~5e-4)
__device__ __forceinline__ float fast_gelu(float v) {
  const float t = 1.5957691216f * v * (1.0f + 0.044715f * v * v);
  return v * __builtin_amdgcn_rcpf(1.0f + __expf(-t));
}

// ---------------- merged prep: x cvt+pool partials, w1/w2 transpose+cvt ----------------
__global__ void prep_kernel(const float* __restrict__ x, bf16_t* __restrict__ xbf,
                            float* __restrict__ pool,
                            const float* __restrict__ w1, bf16_t* __restrict__ w1t,
                            const float* __restrict__ w2, bf16_t* __restrict__ w2t) {
  const int id = blockIdx.x;
  const int tid = threadIdx.x;
  if (id < 256) {
    const int ch = id & 15, b = id >> 4;
    const int cg = tid & 127;
    const int rg = tid >> 7;
    const size_t base = ((size_t)b * S_ + (size_t)ch * 128 + rg * 32) * D_ + cg * 4;
    const float* xp = x + base;
    bf16_t* op = xbf + base;
    float s0 = 0.f, s1 = 0.f, s2 = 0.f, s3 = 0.f;
#pragma unroll 4
    for (int r = 0; r < 32; ++r) {
      float4 v = *reinterpret_cast<const float4*>(xp + (size_t)r * D_);
      s0 += v.x; s1 += v.y; s2 += v.z; s3 += v.w;
      bf16x4v o;
      o[0] = (bf16_t)v.x; o[1] = (bf16_t)v.y; o[2] = (bf16_t)v.z; o[3] = (bf16_t)v.w;
      *reinterpret_cast<bf16x4v*>(op + (size_t)r * D_) = o;
    }
    float* pp = pool + ((size_t)b * 64 + ch * 4 + rg) * D_ + cg * 4;
    pp[0] = s0; pp[1] = s1; pp[2] = s2; pp[3] = s3;
    return;
  }
  int t = id - 256;
  const float* in; bf16_t* outp; int R, C, r0, c0;
  if (t < 1024) {
    const int e = t >> 7, u = t & 127;
    R = D_; C = H_;
    r0 = (u >> 4) * 64; c0 = (u & 15) * 128;
    in = w1 + (size_t)e * R * C; outp = w1t + (size_t)e * R * C;
  } else {
    t -= 1024;
    const int e = t >> 7, u = t & 127;
    R = H_; C = D_;
    r0 = (u >> 2) * 64; c0 = (u & 3) * 128;
    in = w2 + (size_t)e * R * C; outp = w2t + (size_t)e * R * C;
  }
  const int cb2 = tid >> 4;   // 0..31
  const int rb  = tid & 15;   // 0..15
  const float* ip = in + (size_t)(r0 + rb * 4) * C + c0 + cb2 * 4;
  f32x4 v0 = *reinterpret_cast<const f32x4*>(ip);
  f32x4 v1 = *reinterpret_cast<const f32x4*>(ip + C);
  f32x4 v2 = *reinterpret_cast<const f32x4*>(ip + 2 * C);
  f32x4 v3 = *reinterpret_cast<const f32x4*>(ip + 3 * C);
  bf16_t* opb = outp + (size_t)(c0 + cb2 * 4) * R + r0 + rb * 4;
#pragma unroll
  for (int i = 0; i < 4; ++i) {
    bf16x4v o;
    o[0] = (bf16_t)v0[i]; o[1] = (bf16_t)v1[i]; o[2] = (bf16_t)v2[i]; o[3] = (bf16_t)v3[i];
    *reinterpret_cast<bf16x4v*>(opb + (size_t)i * R) = o;
  }
}

// ---------------- gating: logits + top-2 + softmax (shuffle reduce) ----------------
__global__ void gate_kernel(const float* __restrict__ pool, const float* __restrict__ gw,
                            const float* __restrict__ gb, int* __restrict__ route_e,
                            float* __restrict__ route_w) {
  const int b = blockIdx.x;
  const int d = threadIdx.x;
  const int lane = d & 63, wave = d >> 6;
  float p = 0.f;
#pragma unroll
  for (int c = 0; c < 64; ++c) p += pool[((size_t)b * 64 + c) * D_ + d];
  p *= (1.0f / (float)S_);

  __shared__ float wsum[8][8];
  __shared__ float logits[E_];
#pragma unroll
  for (int e = 0; e < E_; ++e) {
    float v = p * gw[d * E_ + e];
#pragma unroll
    for (int off = 32; off >= 1; off >>= 1) v += __shfl_xor(v, off);
    if (lane == 0) wsum[wave][e] = v;
  }
  __syncthreads();
  if (d < E_) {
    float l = gb[d];
#pragma unroll
    for (int w = 0; w < 8; ++w) l += wsum[w][d];
    logits[d] = l;
  }
  __syncthreads();
  if (d == 0) {
    int i0 = 0; float v0 = logits[0];
    for (int e = 1; e < E_; ++e) if (logits[e] > v0) { v0 = logits[e]; i0 = e; }
    int i1 = -1; float v1 = -3.0e38f;
    for (int e = 0; e < E_; ++e) if (e != i0 && logits[e] > v1) { v1 = logits[e]; i1 = e; }
    const float z = expf(v1 - v0);
    const float inv = 1.0f / (1.0f + z);
    route_e[2 * b] = i0; route_e[2 * b + 1] = i1;
    route_w[2 * b] = inv; route_w[2 * b + 1] = z * inv;
  }
}

// ================= shared GEMM machinery =================
#define GEMM_THREAD_CONSTS() \
  const int tid = threadIdx.x; \
  const int lane = tid & 63; \
  const int wave = tid >> 6; \
  const int wr = wave >> 2; \
  const int wc = wave & 3; \
  const int fl = lane & 15; \
  const int hi = (lane >> 4) & 3; \
  const int flb = fl * 128; \
  const int xorv = (fl & 7) << 4; \
  const int koff0 = (hi * 16) ^ xorv; \
  const int koff1 = (64 + hi * 16) ^ xorv; \
  const int r0s = tid >> 3; \
  const int g0s = ((tid & 7) ^ (r0s & 7)) << 3; \
  const int r1s = 64 + (tid >> 3); \
  const int g1s = ((tid & 7) ^ (r1s & 7)) << 3;

#define STAGE_HALF(g, ld, row0, col0, lo) do { \
  gload_lds16((g) + (size_t)((row0) + r0s) * (ld) + (col0) + g0s, smem + (lo) + tid * 16); \
  gload_lds16((g) + (size_t)((row0) + r1s) * (ld) + (col0) + g1s, smem + (lo) + 8192 + tid * 16); \
} while (0)

#define RD_A(mh) do { \
  const char* _pA = smem + ((((t) & 1) * 2 + wr) << 14); \
  _Pragma("unroll") for (int mq = 0; mq < 4; ++mq) { \
    a[mq][0] = *reinterpret_cast<const bf16x8*>(_pA + (mh) * 8192 + mq * 2048 + flb + koff0); \
    a[mq][1] = *reinterpret_cast<const bf16x8*>(_pA + (mh) * 8192 + mq * 2048 + flb + koff1); \
  } } while (0)

#define RD_B(nh) do { \
  const char* _pB = smem + 65536 + ((((t) & 1) * 2 + (wc >> 1)) << 14) + ((wc & 1) << 13); \
  _Pragma("unroll") for (int nq = 0; nq < 2; ++nq) { \
    bb[nh][nq][0] = *reinterpret_cast<const bf16x8*>(_pB + (nh) * 4096 + nq * 2048 + flb + koff0); \
    bb[nh][nq][1] = *reinterpret_cast<const bf16x8*>(_pB + (nh) * 4096 + nq * 2048 + flb + koff1); \
  } } while (0)

#define MFMA_Q(mh, nh) do { \
  _Pragma("unroll") for (int mq = 0; mq < 4; ++mq) \
  _Pragma("unroll") for (int nq = 0; nq < 2; ++nq) { \
    acc[(mh)*4+mq][(nh)*2+nq] = __builtin_amdgcn_mfma_f32_16x16x32_bf16( \
        a[mq][0], bb[nh][nq][0], acc[(mh)*4+mq][(nh)*2+nq], 0, 0, 0); \
    acc[(mh)*4+mq][(nh)*2+nq] = __builtin_amdgcn_mfma_f32_16x16x32_bf16( \
        a[mq][1], bb[nh][nq][1], acc[(mh)*4+mq][(nh)*2+nq], 0, 0, 0); \
  } } while (0)

// ---------------- GEMM1: 256x256 tiles + fast GELU -> h(bf16), LDS-repacked stores ----
// NTM m-tiles x NTN n-tiles per group. A rows offset by mbase; C rows local to launch.
template<int NTM, int NTN>
__global__ __launch_bounds__(512, 2) void gemm1_kernel(
    const bf16_t* __restrict__ xbf, const bf16_t* __restrict__ w1t,
    const float* __restrict__ b1, const int* __restrict__ route_e,
    bf16_t* __restrict__ h_ws, int g0, int mbase, size_t cstride) {
  __shared__ alignas(16) char smem[131072];
  const int TILES = NTM * NTN;
  const int nwg = gridDim.x;
  const int id = blockIdx.x;
  const int swz = (id & 7) * (nwg >> 3) + (id >> 3);
  const int lg = swz / TILES;
  const int tile = swz % TILES;
  const int m0 = (tile / NTN) * 256;
  const int n0 = (tile % NTN) * 256;
  const int g = g0 + lg;
  const int b = g >> 1;
  const int e = route_e[g];
  const bf16_t* Ax = xbf + (size_t)b * S_ * D_;
  const bf16_t* Bw = w1t + (size_t)e * H_ * D_;
  bf16_t* C = h_ws + (size_t)lg * cstride;

  GEMM_THREAD_CONSTS();

  f32x4 acc[8][4];
#pragma unroll
  for (int i = 0; i < 8; ++i)
#pragma unroll
    for (int j = 0; j < 4; ++j) acc[i][j] = f32x4{0.f, 0.f, 0.f, 0.f};
  bf16x8 a[4][2], bb[2][2][2];

#define ST_A1(tt, hh) STAGE_HALF(Ax, D_, mbase + m0 + (hh) * 128, (tt) * 64, ((((tt) & 1) * 2 + (hh)) << 14))
#define ST_B1(tt, hh) STAGE_HALF(Bw, D_, n0 + (hh) * 128, (tt) * 64, 65536 + ((((tt) & 1) * 2 + (hh)) << 14))

  const int NT = D_ / 64;  // 8
  ST_A1(0, 0); ST_A1(0, 1); ST_B1(0, 0); ST_B1(0, 1);
  ST_B1(1, 0); ST_B1(1, 1);
  VM4(); BAR();

  for (int t = 0; t < NT; ++t) {
    RD_A(0); RD_B(0);
    if (t + 1 < NT) ST_A1(t + 1, 0);
    BAR(); LGKM0(); PRIO1(); MFMA_Q(0, 0); PRIO0(); BAR();
    RD_B(1);
    if (t + 1 < NT) ST_A1(t + 1, 1);
    BAR(); LGKM0(); PRIO1(); MFMA_Q(0, 1); PRIO0(); BAR();
    RD_A(1);
    if (t + 2 < NT) ST_B1(t + 2, 0);
    BAR(); LGKM0(); PRIO1(); MFMA_Q(1, 0); PRIO0(); BAR();
    if (t + 2 < NT) ST_B1(t + 2, 1);
    if (t < NT - 2) { VM4(); } else if (t == NT - 2) { VM0(); }
    BAR(); PRIO1(); MFMA_Q(1, 1); PRIO0(); BAR();
  }
#undef ST_A1
#undef ST_B1

  // epilogue: bias + fast GELU -> LDS [256][512B] (XOR bits 6:5 by (row>>2)&3) -> 16B stores
  const int rb2 = hi * 4;
#pragma unroll
  for (int ni = 0; ni < 4; ++ni) {
    const int col = wc * 64 + ni * 16 + fl;
    const float bias = b1[e * H_ + n0 + col];
    const int cb = col * 2;
#pragma unroll
    for (int mi = 0; mi < 8; ++mi) {
#pragma unroll
      for (int j = 0; j < 4; ++j) {
        const int row = wr * 128 + mi * 16 + rb2 + j;
        const float v = acc[mi][ni][j] + bias;
        const int ad = (row << 9) + (cb ^ (((row >> 2) & 3) << 5));
        *reinterpret_cast<bf16_t*>(smem + ad) = (bf16_t)fast_gelu(v);
      }
    }
  }
  LGKMW(); BAR();
#pragma unroll
  for (int i = 0; i < 16; ++i) {
    const int byte = i * 8192 + tid * 16;
    const int row = byte >> 9;
    const int colb = byte & 511;
    const int ad = (row << 9) + (colb ^ (((row >> 2) & 3) << 5));
    const bf16x8 vv = *reinterpret_cast<const bf16x8*>(smem + ad);
    *reinterpret_cast<bf16x8*>((char*)C + ((size_t)(m0 + row) * H_ + n0) * 2 + colb) = vv;
  }
}

// ---------------- GEMM2s: BM=128, BN=256, full-K (2 experts), no RMW ----------------
template<int KNT>
__global__ __launch_bounds__(512, 2) void gemm2s_kernel(
    const bf16_t* __restrict__ h_ws, const bf16_t* __restrict__ w2t,
    const float* __restrict__ b2, const int* __restrict__ route_e,
    const float* __restrict__ route_w, float* __restrict__ out, int srow) {
  __shared__ alignas(16) char smem[98304];
  const int nwg = gridDim.x;
  const int id = blockIdx.x;
  const int swz = (id & 7) * (nwg >> 3) + (id >> 3);
  const int lb = swz >> 4;
  const int tile = swz & 15;
  const int m0 = (tile >> 1) * 128;
  const int n0 = (tile & 1) * 256;
  const int e0 = route_e[2 * lb], e1 = route_e[2 * lb + 1];
  const float wg0 = route_w[2 * lb], wg1 = route_w[2 * lb + 1];
  const float ratio = wg1 / wg0;
  const bf16_t* Ae1 = h_ws + (size_t)(lb * 2 + 1) * 1024 * H_;
  const bf16_t* Ae0 = h_ws + (size_t)(lb * 2 + 0) * 1024 * H_;
  const bf16_t* Be1 = w2t + (size_t)e1 * D_ * H_;
  const bf16_t* Be0 = w2t + (size_t)e0 * D_ * H_;

  GEMM_THREAD_CONSTS();
  (void)koff1;

  f32x4 acc[4][4];
#pragma unroll
  for (int i = 0; i < 4; ++i)
#pragma unroll
    for (int j = 0; j < 4; ++j) acc[i][j] = f32x4{0.f, 0.f, 0.f, 0.f};
  bf16x8 a[4][2], bb[2][2][2];

  const int KH = KNT / 2;  // 32

#define ST_A2S(tt) do { const bf16_t* _ab = ((tt) < KH) ? Ae1 : Ae0; \
  STAGE_HALF(_ab, H_, m0, ((tt) & (KH - 1)) * 64, (((tt) & 1) << 14)); } while (0)
#define ST_B2S(tt, hh) do { const bf16_t* _bbp = ((tt) < KH) ? Be1 : Be0; \
  STAGE_HALF(_bbp, H_, n0 + (hh) * 128, ((tt) & (KH - 1)) * 64, 32768 + ((((tt) & 1) * 2 + (hh)) << 14)); } while (0)

#define RD_AS() do { \
  const char* _pA = smem + (((t) & 1) << 14); \
  _Pragma("unroll") for (int mq = 0; mq < 4; ++mq) { \
    a[mq][0] = *reinterpret_cast<const bf16x8*>(_pA + wr * 8192 + mq * 2048 + flb + koff0); \
    a[mq][1] = *reinterpret_cast<const bf16x8*>(_pA + wr * 8192 + mq * 2048 + flb + koff1); \
  } } while (0)

#define RD_BS(nh) do { \
  const char* _pB = smem + 32768 + ((((t) & 1) * 2 + (wc >> 1)) << 14) + ((wc & 1) << 13); \
  _Pragma("unroll") for (int nq = 0; nq < 2; ++nq) { \
    bb[nh][nq][0] = *reinterpret_cast<const bf16x8*>(_pB + (nh) * 4096 + nq * 2048 + flb + koff0); \
    bb[nh][nq][1] = *reinterpret_cast<const bf16x8*>(_pB + (nh) * 4096 + nq * 2048 + flb + koff1); \
  } } while (0)

#define MFMA_S(nh) do { \
  _Pragma("unroll") for (int mq = 0; mq < 4; ++mq) \
  _Pragma("unroll") for (int nq = 0; nq < 2; ++nq) { \
    acc[mq][(nh)*2+nq] = __builtin_amdgcn_mfma_f32_16x16x32_bf16( \
        a[mq][0], bb[nh][nq][0], acc[mq][(nh)*2+nq], 0, 0, 0); \
    acc[mq][(nh)*2+nq] = __builtin_amdgcn_mfma_f32_16x16x32_bf16( \
        a[mq][1], bb[nh][nq][1], acc[mq][(nh)*2+nq], 0, 0, 0); \
  } } while (0)

  const int NT = KNT;
  ST_A2S(0); ST_B2S(0, 0); ST_B2S(0, 1);
  ST_B2S(1, 0); ST_B2S(1, 1);
  VM4(); BAR();

  for (int t = 0; t < NT; ++t) {
    RD_AS(); RD_BS(0);
    if (t + 1 < NT) ST_A2S(t + 1);
    LGKM8(); BAR(); LGKM0(); PRIO1(); MFMA_S(0); PRIO0(); BAR();
    RD_BS(1);
    if (t + 2 < NT) { ST_B2S(t + 2, 0); ST_B2S(t + 2, 1); }
    if (t < NT - 2) { VM4(); } else if (t == NT - 2) { VM0(); }
    BAR(); LGKM0(); PRIO1(); MFMA_S(1); PRIO0();
    if (t == KH - 1) {
#pragma unroll
      for (int i = 0; i < 4; ++i)
#pragma unroll
        for (int j = 0; j < 4; ++j) acc[i][j] = acc[i][j] * ratio;
    }
    BAR();
  }
#undef ST_A2S
#undef ST_B2S
#undef RD_AS
#undef RD_BS
#undef MFMA_S

  const int rb2 = hi * 4;
  float* Co = out + (size_t)lb * S_ * D_;
#pragma unroll
  for (int ni = 0; ni < 4; ++ni) {
    const int gc = n0 + wc * 64 + ni * 16 + fl;
    const float wb = wg0 * b2[e0 * D_ + gc] + wg1 * b2[e1 * D_ + gc];
#pragma unroll
    for (int mq = 0; mq < 4; ++mq) {
#pragma unroll
      for (int j = 0; j < 4; ++j) {
        const int gr = srow + m0 + wr * 64 + mq * 16 + rb2 + j;
        Co[(size_t)gr * D_ + gc] = wg0 * acc[mq][ni][j] + wb;
      }
    }
  }
}

// ---------------- legacy GEMM2 (per-sample fallback path) ----------------
template<int KNT>
__global__ __launch_bounds__(512, 2) void gemm2_kernel(
    const bf16_t* __restrict__ h_ws, const bf16_t* __restrict__ w2t,
    const float* __restrict__ b2, const int* __restrict__ route_e,
    const float* __restrict__ route_w, float* __restrict__ out, int b0) {
  __shared__ alignas(16) char smem[131072];
  const int nwg = gridDim.x;
  const int id = blockIdx.x;
  const int swz = (id & 7) * (nwg >> 3) + (id >> 3);
  const int lb = swz >> 4;
  const int tile = swz & 15;
  const int m0 = (tile >> 1) * 256;
  const int n0 = (tile & 1) * 256;
  const int smp = b0 + lb;
  const int e0 = route_e[2 * smp], e1 = route_e[2 * smp + 1];
  const float wg0 = route_w[2 * smp], wg1 = route_w[2 * smp + 1];
  const float ratio = wg1 / wg0;
  const bf16_t* Ae1 = h_ws + (size_t)(lb * 2 + 1) * S_ * H_;
  const bf16_t* Ae0 = h_ws + (size_t)(lb * 2 + 0) * S_ * H_;
  const bf16_t* Be1 = w2t + (size_t)e1 * D_ * H_;
  const bf16_t* Be0 = w2t + (size_t)e0 * D_ * H_;

  GEMM_THREAD_CONSTS();

  f32x4 acc[8][4];
#pragma unroll
  for (int i = 0; i < 8; ++i)
#pragma unroll
    for (int j = 0; j < 4; ++j) acc[i][j] = f32x4{0.f, 0.f, 0.f, 0.f};
  bf16x8 a[4][2], bb[2][2][2];

  const int KH = KNT / 2;

#define ST_A2(tt, hh) do { const bf16_t* _ab = ((tt) < KH) ? Ae1 : Ae0; \
  STAGE_HALF(_ab, H_, m0 + (hh) * 128, ((tt) & (KH - 1)) * 64, ((((tt) & 1) * 2 + (hh)) << 14)); } while (0)
#define ST_B2(tt, hh) do { const bf16_t* _bbp = ((tt) < KH) ? Be1 : Be0; \
  STAGE_HALF(_bbp, H_, n0 + (hh) * 128, ((tt) & (KH - 1)) * 64, 65536 + ((((tt) & 1) * 2 + (hh)) << 14)); } while (0)

  const int NT = KNT;
  ST_A2(0, 0); ST_A2(0, 1); ST_B2(0, 0); ST_B2(0, 1);
  ST_B2(1, 0); ST_B2(1, 1);
  VM4(); BAR();

  for (int t = 0; t < NT; ++t) {
    RD_A(0); RD_B(0);
    if (t + 1 < NT) ST_A2(t + 1, 0);
    BAR(); LGKM0(); PRIO1(); MFMA_Q(0, 0); PRIO0(); BAR();
    RD_B(1);
    if (t + 1 < NT) ST_A2(t + 1, 1);
    BAR(); LGKM0(); PRIO1(); MFMA_Q(0, 1); PRIO0(); BAR();
    RD_A(1);
    if (t + 2 < NT) ST_B2(t + 2, 0);
    BAR(); LGKM0(); PRIO1(); MFMA_Q(1, 0); PRIO0(); BAR();
    if (t + 2 < NT) ST_B2(t + 2, 1);
    if (t < NT - 2) { VM4(); } else if (t == NT - 2) { VM0(); }
    BAR(); PRIO1(); MFMA_Q(1, 1); PRIO0();
    if (t == KH - 1) {
#pragma unroll
      for (int i = 0; i < 8; ++i)
#pragma unroll
        for (int j = 0; j < 4; ++j) acc[i][j] = acc[i][j] * ratio;
    }
    BAR();
  }
#undef ST_A2
#undef ST_B2

  const int rb2 = hi * 4;
  float* Co = out + (size_t)smp * S_ * D_;
#pragma unroll
  for (int ni = 0; ni < 4; ++ni) {
    const int gc = n0 + wc * 64 + ni * 16 + fl;
    const float wb = wg0 * b2[e0 * D_ + gc] + wg1 * b2[e1 * D_ + gc];
#pragma unroll
    for (int mi = 0; mi < 8; ++mi) {
#pragma unroll
      for (int j = 0; j < 4; ++j) {
        const int gr = m0 + wr * 128 + mi * 16 + rb2 + j;
        Co[(size_t)gr * D_ + gc] = wg0 * acc[mi][ni][j] + wb;
      }
    }
  }
}

extern "C" void kernel_launch(void* const* d_in, const int* in_sizes, int n_in,
                              void* d_out, int out_size, void* d_ws, size_t ws_size,
                              hipStream_t stream) {
  const float* x      = (const float*)d_in[0];
  const float* gate_w = (const float*)d_in[1];
  const float* gate_b = (const float*)d_in[2];
  const float* w1     = (const float*)d_in[3];
  const float* b1     = (const float*)d_in[4];
  const float* w2     = (const float*)d_in[5];
  const float* b2     = (const float*)d_in[6];
  float* out = (float*)d_out;
  char* ws = (char*)d_ws;

  bf16_t* xbf    = (bf16_t*)(ws);                 // 33,554,432
  bf16_t* w1t    = (bf16_t*)(ws + 33554432);      // 16,777,216
  bf16_t* w2t    = (bf16_t*)(ws + 50331648);      // 16,777,216
  float*  pool   = (float*)(ws + 67108864);       // 2,097,152
  int*    route_e = (int*)(ws + 69206016);
  float*  route_w = (float*)(ws + 69206144);
  const size_t h_off = 69206272;
  bf16_t* h_ws   = (bf16_t*)(ws + h_off);

  prep_kernel<<<2304, 512, 0, stream>>>(x, xbf, pool, w1, w1t, w2, w2t);
  gate_kernel<<<B_, 512, 0, stream>>>(pool, gate_w, gate_b, route_e, route_w);

  const bool split = ws_size >= h_off + (size_t)134217728;  // h row-half = 128 MiB
  if (split) {
    // S-split pipeline: gemm1 full-H for a row-half, gemm2s full-K no-RMW. All full-GPU.
    gemm1_kernel<4, 8><<<1024, 512, 0, stream>>>(xbf, w1t, b1, route_e, h_ws, 0, 0, (size_t)1024 * H_);
    gemm2s_kernel<64><<<256, 512, 0, stream>>>(h_ws, w2t, b2, route_e, route_w, out, 0);
    gemm1_kernel<4, 8><<<1024, 512, 0, stream>>>(xbf, w1t, b1, route_e, h_ws, 0, 1024, (size_t)1024 * H_);
    gemm2s_kernel<64><<<256, 512, 0, stream>>>(h_ws, w2t, b2, route_e, route_w, out, 1024);
  } else {
    const size_t per_b = (size_t)2 * S_ * H_ * sizeof(bf16_t);
    size_t avail = (ws_size > h_off) ? (ws_size - h_off) : 0;
    int nb = (int)(avail / per_b);
    if (nb < 1) nb = 1;
    if (nb > B_) nb = B_;
    for (int b0 = 0; b0 < B_; b0 += nb) {
      const int cb = (B_ - b0 < nb) ? (B_ - b0) : nb;
      gemm1_kernel<8, 8><<<64 * cb * 2, 512, 0, stream>>>(xbf, w1t, b1, route_e, h_ws, b0 * 2, 0, (size_t)S_ * H_);
      gemm2_kernel<64><<<16 * cb, 512, 0, stream>>>(h_ws, w2t, b2, route_e, route_w, out, b0);
    }
  }
}